// Round 5
// baseline (135.713 us; speedup 1.0000x reference)
//
#include <hip/hip_runtime.h>
#include <cstdint>
#include <cstddef>

#define NPTS   4096
#define BATCH  4
#define KNN    8
#define EPS_F  1e-12f

__device__ __forceinline__ uint32_t u32min(uint32_t a, uint32_t b) { return a < b ? a : b; }
__device__ __forceinline__ uint32_t u32max(uint32_t a, uint32_t b) { return a > b ? a : b; }
__device__ __forceinline__ unsigned long long u64min(unsigned long long a, unsigned long long b) { return a < b ? a : b; }
__device__ __forceinline__ unsigned long long u64max(unsigned long long a, unsigned long long b) { return a > b ? a : b; }

// v_med3_u32: for sorted a<=b, med3(a,b,x) == clamp(x,a,b) — one instruction.
__device__ __forceinline__ uint32_t umed3(uint32_t a, uint32_t b, uint32_t c) {
  uint32_t d;
  asm("v_med3_u32 %0, %1, %2, %3" : "=v"(d) : "v"(a), "v"(b), "v"(c));
  return d;
}

// Insert key into ascending 9-list, dropping the largest: 1 min + 8 med3.
__device__ __forceinline__ void insert9(uint32_t loc[KNN + 1], uint32_t key) {
  uint32_t prev = loc[0];
  loc[0] = u32min(prev, key);
#pragma unroll
  for (int m = 1; m <= KNN; ++m) {
    const uint32_t cur = loc[m];
    loc[m] = umed3(prev, cur, key);
    prev = cur;
  }
}

// ---------------------------------------------------------------------------
// Kernel 1: per-(cloud,batch,point,chunk) top-9 (incl. self) by truncated key.
// Key = (float_bits(d2) & 0xFFFFF000) | j. Ties break ascending j (lax.top_k).
// Self has d2 == +0 exactly -> rank-0 in its own chunk; dropped there.
// Block 0 zeroes acc/ticket (replaces memset node).
// ---------------------------------------------------------------------------
template <int NC>
__global__ void __launch_bounds__(256, 4)
knn_partial_t(const float* __restrict__ pred, const float* __restrict__ tgt,
              uint32_t* __restrict__ partial, double* __restrict__ acc,
              uint32_t* __restrict__ ticket) {
  constexpr int CHN = NPTS / NC;
  if (blockIdx.x == 0 && threadIdx.x == 0) {
    acc[0] = 0.0; acc[1] = 0.0; acc[2] = 0.0;
    *ticket = 0u;
  }

  int bx = blockIdx.x;
  const int chunk = bx % NC; bx /= NC;
  const int ig    = bx & 15; bx >>= 4;
  const int b     = bx & 3;  bx >>= 2;
  const int cloud = bx;  // 0 = pred, 1 = target

  const float* __restrict__ pts = (cloud ? tgt : pred) + (size_t)b * NPTS * 3;
  const int tid = threadIdx.x;
  const int i = ig * 256 + tid;
  const int j0 = chunk * CHN;

  const float xix = pts[3 * i + 0];
  const float xiy = pts[3 * i + 1];
  const float xiz = pts[3 * i + 2];

  uint32_t loc[KNN + 1];
#pragma unroll
  for (int k = 0; k <= KNN; ++k) loc[k] = 0xFFFFFFFFu;

  // j0*3*4 bytes is 16B-aligned (j0 multiple of 256).
  const float4* __restrict__ c4 = (const float4*)(pts + 3 * j0);

#pragma unroll 8
  for (int t4 = 0; t4 < CHN / 4; ++t4) {
    const float4 q0 = c4[3 * t4 + 0];  // x0 y0 z0 x1
    const float4 q1 = c4[3 * t4 + 1];  // y1 z1 x2 y2
    const float4 q2 = c4[3 * t4 + 2];  // z2 x3 y3 z3
    const uint32_t jb = (uint32_t)(j0 + 4 * t4);
    {
      const float dx = xix - q0.x, dy = xiy - q0.y, dz = xiz - q0.z;
      const float d2 = fmaf(dx, dx, fmaf(dy, dy, dz * dz));
      insert9(loc, (__float_as_uint(d2) & 0xFFFFF000u) | (jb + 0u));
    }
    {
      const float dx = xix - q0.w, dy = xiy - q1.x, dz = xiz - q1.y;
      const float d2 = fmaf(dx, dx, fmaf(dy, dy, dz * dz));
      insert9(loc, (__float_as_uint(d2) & 0xFFFFF000u) | (jb + 1u));
    }
    {
      const float dx = xix - q1.z, dy = xiy - q1.w, dz = xiz - q2.x;
      const float d2 = fmaf(dx, dx, fmaf(dy, dy, dz * dz));
      insert9(loc, (__float_as_uint(d2) & 0xFFFFF000u) | (jb + 2u));
    }
    {
      const float dx = xix - q2.y, dy = xiy - q2.z, dz = xiz - q2.w;
      const float d2 = fmaf(dx, dx, fmaf(dy, dy, dz * dz));
      insert9(loc, (__float_as_uint(d2) & 0xFFFFF000u) | (jb + 3u));
    }
  }

  const bool self_chunk = ((ig * 256) / CHN) == chunk;
  uint4 o0, o1;
  if (self_chunk) {
    o0 = make_uint4(loc[1], loc[2], loc[3], loc[4]);
    o1 = make_uint4(loc[5], loc[6], loc[7], loc[8]);
  } else {
    o0 = make_uint4(loc[0], loc[1], loc[2], loc[3]);
    o1 = make_uint4(loc[4], loc[5], loc[6], loc[7]);
  }
  uint32_t* p = partial +
      ((((size_t)(cloud * BATCH + b) * NC + chunk) * NPTS) + (size_t)i) * KNN;
  *(uint4*)p = o0;
  *(uint4*)(p + 4) = o1;
}

// 12-CE bitonic cleanup for an 8-list whose halves came from a bitonic merge.
__device__ __forceinline__ void cleanup8(uint32_t t[KNN]) {
#define CEU(x, y) { uint32_t lo = u32min(t[x], t[y]); uint32_t hi = u32max(t[x], t[y]); t[x] = lo; t[y] = hi; }
  CEU(0,4) CEU(1,5) CEU(2,6) CEU(3,7)
  CEU(0,2) CEU(1,3) CEU(4,6) CEU(5,7)
  CEU(0,1) CEU(2,3) CEU(4,5) CEU(6,7)
#undef CEU
}

// Batcher odd-even mergesort, 8 elements, 19 compare-exchanges.
__device__ __forceinline__ void sort8(unsigned long long s[8]) {
#define CE(a, b) { unsigned long long lo = u64min(s[a], s[b]); \
                   unsigned long long hi = u64max(s[a], s[b]); s[a] = lo; s[b] = hi; }
  CE(0,1) CE(2,3) CE(0,2) CE(1,3) CE(1,2)
  CE(4,5) CE(6,7) CE(4,6) CE(5,7) CE(5,6)
  CE(0,4) CE(1,5) CE(2,6) CE(3,7)
  CE(2,4) CE(3,5)
  CE(1,2) CE(3,4) CE(5,6)
#undef CE
}

// ---------------------------------------------------------------------------
// Kernel 2: 8 threads per point. Lane role r = cloud*4 + chunk-group.
// Each lane merges NC/4 chunks serially (sorted result), then xor1/xor2
// shuffle-merges combine within the cloud; xor4 exchanges clouds.
// ---------------------------------------------------------------------------
template <int NC>
__global__ void __launch_bounds__(256, 4)
loss_t(const float* __restrict__ pred, const float* __restrict__ tgt,
       const uint32_t* __restrict__ partial, double* __restrict__ acc,
       uint32_t* __restrict__ ticket, float* __restrict__ out) {
  constexpr int NCG = NC / 4;  // chunks per lane
  const int g = blockIdx.x * 256 + threadIdx.x;   // 0 .. 131071
  const int r = g & 7;                            // lane role
  const int cloud = r >> 2;
  const int cg    = r & 3;
  const int p = g >> 3;                           // 0 .. 16383
  const int b = p >> 12;
  const int i = p & (NPTS - 1);

  const float* __restrict__ P = pred + (size_t)b * NPTS * 3;
  const float* __restrict__ T = tgt  + (size_t)b * NPTS * 3;
  const float* __restrict__ C = cloud ? T : P;

  // ---- serial merge of this lane's NCG chunks (keep sorted at every step)
  uint32_t v[KNN];
  {
    const uint32_t* base = partial +
        (((size_t)(cloud * BATCH + b) * NC + (size_t)cg * NCG) * NPTS + (size_t)i) * KNN;
    const uint4 a0 = *(const uint4*)base, a1 = *(const uint4*)(base + 4);
    v[0] = a0.x; v[1] = a0.y; v[2] = a0.z; v[3] = a0.w;
    v[4] = a1.x; v[5] = a1.y; v[6] = a1.z; v[7] = a1.w;
#pragma unroll
    for (int c = 1; c < NCG; ++c) {
      const uint32_t* pc = base + (size_t)c * NPTS * KNN;
      const uint4 l0 = *(const uint4*)pc, l1 = *(const uint4*)(pc + 4);
      const uint32_t L[KNN] = {l0.x, l0.y, l0.z, l0.w, l1.x, l1.y, l1.z, l1.w};
      uint32_t t[KNN];
#pragma unroll
      for (int m = 0; m < KNN; ++m) t[m] = u32min(v[m], L[KNN - 1 - m]);
      cleanup8(t);
#pragma unroll
      for (int m = 0; m < KNN; ++m) v[m] = t[m];
    }
  }

  // ---- shuffle-merge within cloud: xor1 (cleanup), xor2 (set only)
#pragma unroll
  for (int lvl = 0; lvl < 2; ++lvl) {
    const int mask = 1 << lvl;
    uint32_t o[KNN];
#pragma unroll
    for (int m = 0; m < KNN; ++m) o[m] = __shfl_xor(v[m], mask);
    uint32_t t[KNN];
#pragma unroll
    for (int m = 0; m < KNN; ++m) t[m] = u32min(v[m], o[KNN - 1 - m]);
    if (lvl == 0) cleanup8(t);
#pragma unroll
    for (int m = 0; m < KNN; ++m) v[m] = t[m];
  }

  // ---- exact recompute + sort (replicated across the cloud's 4 lanes)
  const float cx = C[3 * i], cy = C[3 * i + 1], cz = C[3 * i + 2];
  const float sq = cx * cx + cy * cy + cz * cz;
  unsigned long long k8[KNN];
#pragma unroll
  for (int k = 0; k < KNN; ++k) {
    const int j = (int)(v[k] & 0xFFFu);
    const float x = C[3 * j], y = C[3 * j + 1], z = C[3 * j + 2];
    const float d2 = sq + (x * x + y * y + z * z) - 2.0f * (cx * x + cy * y + cz * z);
    const float dist = sqrtf(fmaxf(d2, EPS_F));
    k8[k] = ((unsigned long long)__float_as_uint(dist) << 12) | (unsigned long long)j;
  }
  sort8(k8);

  // ---- per-cloud sums: density distance sum + covariance (6 uniques)
  int jnb[KNN];
  float dsum = 0.f, cov[6] = {0, 0, 0, 0, 0, 0};
#pragma unroll
  for (int k = 0; k < KNN; ++k) {
    const int j = (int)(k8[k] & 0xFFFu);
    jnb[k] = j;
    dsum += __uint_as_float((uint32_t)(k8[k] >> 12));
    const float ax = C[3 * j] - cx, ay = C[3 * j + 1] - cy, az = C[3 * j + 2] - cz;
    cov[0] += ax * ax; cov[1] += ay * ay; cov[2] += az * az;
    cov[3] += ax * ay; cov[4] += ax * az; cov[5] += ay * az;
  }

  // ---- exchange with partner cloud (xor4)
  int jo[KNN];
#pragma unroll
  for (int k = 0; k < KNN; ++k) jo[k] = __shfl_xor(jnb[k], 4);
  const float dsum_o = __shfl_xor(dsum, 4);
  float cov_o[6];
#pragma unroll
  for (int k = 0; k < 6; ++k) cov_o[k] = __shfl_xor(cov[k], 4);

  // ---- direction term: lane r computes neighbor k = r (one of 8)
  float s;
  {
    const int k = r;
    const int jp = (cloud == 0) ? jnb[k] : jo[k];
    const int jt = (cloud == 0) ? jo[k] : jnb[k];
    const float pix = P[3 * i], piy = P[3 * i + 1], piz = P[3 * i + 2];
    const float tix = T[3 * i], tiy = T[3 * i + 1], tiz = T[3 * i + 2];
    const float ax = P[3 * jp] - pix, ay = P[3 * jp + 1] - piy, az = P[3 * jp + 2] - piz;
    const float bx = T[3 * jt] - tix, by = T[3 * jt + 1] - tiy, bz = T[3 * jt + 2] - tiz;
    const float ai = 1.0f / fmaxf(sqrtf(ax * ax + ay * ay + az * az), EPS_F);
    const float bi = 1.0f / fmaxf(sqrtf(bx * bx + by * by + bz * bz), EPS_F);
    s = (ax * bx + ay * by + az * bz) * (ai * bi);
  }

  // ---- density + curvature terms (lane r==0 only, others contribute 0)
  float e = 0.f, cfro = 0.f;
  {
    const float dsp = (cloud == 0) ? dsum : dsum_o;
    const float dst = (cloud == 0) ? dsum_o : dsum;
    const float densp = dsp * (1.0f / KNN), denst = dst * (1.0f / KNN);
    float dxx = (cov[0] - cov_o[0]) * (1.0f / KNN);
    float dyy = (cov[1] - cov_o[1]) * (1.0f / KNN);
    float dzz = (cov[2] - cov_o[2]) * (1.0f / KNN);
    float dxy = (cov[3] - cov_o[3]) * (1.0f / KNN);
    float dxz = (cov[4] - cov_o[4]) * (1.0f / KNN);
    float dyz = (cov[5] - cov_o[5]) * (1.0f / KNN);
    const float ev = (densp - denst) * (densp - denst);
    const float cv = sqrtf(dxx * dxx + dyy * dyy + dzz * dzz
                           + 2.0f * (dxy * dxy + dxz * dxz + dyz * dyz));
    e    = (r == 0) ? ev : 0.f;
    cfro = (r == 0) ? cv : 0.f;
  }

  // ---- block reduce (4 waves) + atomic + ticket finalize
#pragma unroll
  for (int off = 32; off > 0; off >>= 1) {
    e    += __shfl_down(e, off);
    s    += __shfl_down(s, off);
    cfro += __shfl_down(cfro, off);
  }
  __shared__ float red[12];
  const int w = threadIdx.x >> 6;
  if ((threadIdx.x & 63) == 0) { red[w] = e; red[4 + w] = s; red[8 + w] = cfro; }
  __syncthreads();
  if (threadIdx.x == 0) {
    atomicAdd(&acc[0], (double)(red[0] + red[1] + red[2] + red[3]));
    atomicAdd(&acc[1], (double)(red[4] + red[5] + red[6] + red[7]));
    atomicAdd(&acc[2], (double)(red[8] + red[9] + red[10] + red[11]));
    __threadfence();
    const unsigned rank = atomicAdd(ticket, 1u) + 1u;
    if (rank == gridDim.x) {
      __threadfence();
      const double ee = __hip_atomic_load(&acc[0], __ATOMIC_RELAXED, __HIP_MEMORY_SCOPE_AGENT);
      const double ss = __hip_atomic_load(&acc[1], __ATOMIC_RELAXED, __HIP_MEMORY_SCOPE_AGENT);
      const double cc = __hip_atomic_load(&acc[2], __ATOMIC_RELAXED, __HIP_MEMORY_SCOPE_AGENT);
      const double BN = (double)BATCH * (double)NPTS;
      out[0] = (float)(ee / BN + 0.5 * (1.0 - ss / (BN * (double)KNN)) + 0.5 * (cc / BN));
    }
  }
}

extern "C" void kernel_launch(void* const* d_in, const int* in_sizes, int n_in,
                              void* d_out, int out_size, void* d_ws, size_t ws_size,
                              hipStream_t stream) {
  const float* pred = (const float*)d_in[0];
  const float* tgt  = (const float*)d_in[1];
  double* acc = (double*)d_ws;                       // 3 doubles @ 0
  uint32_t* ticket = (uint32_t*)((char*)d_ws + 64);  // 1 u32 @ 64
  uint32_t* partial = (uint32_t*)((char*)d_ws + 4096);

  const size_t need16 = 4096 + (size_t)2 * BATCH * 16 * NPTS * KNN * sizeof(uint32_t);
  if (ws_size >= need16) {
    knn_partial_t<16><<<2 * BATCH * (NPTS / 256) * 16, 256, 0, stream>>>(
        pred, tgt, partial, acc, ticket);
    loss_t<16><<<(BATCH * NPTS * 8) / 256, 256, 0, stream>>>(
        pred, tgt, partial, acc, ticket, (float*)d_out);
  } else {
    knn_partial_t<8><<<2 * BATCH * (NPTS / 256) * 8, 256, 0, stream>>>(
        pred, tgt, partial, acc, ticket);
    loss_t<8><<<(BATCH * NPTS * 8) / 256, 256, 0, stream>>>(
        pred, tgt, partial, acc, ticket, (float*)d_out);
  }
}